// Round 14
// baseline (1226.791 us; speedup 1.0000x reference)
//
#include <hip/hip_runtime.h>
#include <hip/hip_bf16.h>

#define M_ 4096
#define N_ 32000
#define K_ 4096
#define S_ 2048
#define SM1 2047
#define NROWS 4094
#define NT_ 64   // K-tiles of BK=64
#define NB_ 125  // n-blocks per row

typedef __bf16 bf16x8 __attribute__((ext_vector_type(8)));
typedef float f32x4 __attribute__((ext_vector_type(4)));

#define GLDS16(g, l)                                                         \
  __builtin_amdgcn_global_load_lds(                                          \
      (__attribute__((address_space(1))) const void*)(g),                    \
      (__attribute__((address_space(3))) void*)(l), 16, 0, 0)
#define BAR() __builtin_amdgcn_s_barrier()
#define PRIO1() __builtin_amdgcn_s_setprio(1)
#define PRIO0() __builtin_amdgcn_s_setprio(0)
#define VMCNT(n) asm volatile("s_waitcnt vmcnt(" #n ")" ::: "memory")
#define LGKM0() asm volatile("s_waitcnt lgkmcnt(0)" ::: "memory")

// ---------------------------------------------------------------- cvt kernel
__global__ __launch_bounds__(256) void cvt_f32_to_bf16(
    const float* __restrict__ in, bf16x8* __restrict__ out, long n8) {
  long i0 = (long)blockIdx.x * blockDim.x + threadIdx.x;
  long stride = (long)gridDim.x * blockDim.x;
  for (long i = i0; i < n8; i += stride) {
    const float4* p = reinterpret_cast<const float4*>(in) + i * 2;
    float4 a = p[0];
    float4 b = p[1];
    bf16x8 v;
    v[0] = (__bf16)a.x; v[1] = (__bf16)a.y; v[2] = (__bf16)a.z; v[3] = (__bf16)a.w;
    v[4] = (__bf16)b.x; v[5] = (__bf16)b.y; v[6] = (__bf16)b.z; v[7] = (__bf16)b.w;
    out[i] = v;
  }
}

// ---------------------------------------------------------------- GEMM 256x256, BK=64 — 8-phase, HBM-latency-proof waits
// C[m,n] = sum_k A[m,k]*B[n,k]. 512 thr = 8 waves (2m x 4n), per-wave 128x64
// = acc[8][4]. LDS 2 x 64KB (A 32K | B 32K), 128-B rows, slot = c ^ (row&7)
// (measured-conflict-free: linear GLDS dest + inverse-swz source).
//
// Halfsets (2 GLDS/thread each): SA0=A rows bit6==0 (al), SA1=bit6==1 (ah),
// SB0=B rows bit5==0 (b0), SB1=bit5==1 (b1).
//
// R14: R13's phase skeleton, but stages/waits placed so EVERY wait retires
// only loads aged >=6 phases (~930cy >= HBM-miss latency; R13's single
// VMCNT(6) covered a 3-phase-old load, ~465cy -> per-tile stall at N=32000
// where B (250MB) is not L3-resident).
//   During tile s, stage tile s+2 into buf[cur] (same parity):
//     ph2: SA0,SB0(s+2)   ph3: SB1(s+2)   ph4: SA1(s+2)   (ph1: none)
//   Reads (phase start): ph1: b0r(4)+al(8); ph2: b1r(4); ph3: ah(8); ph4: 0.
//   Waits: W_b=VMCNT(10)@ph1-end retires SB1(s)   [staged ph3(s-2), 6ph]
//          W_c=VMCNT(12)@ph2-end retires SA1(s)   [staged ph4(s-2), 6ph]
//          W_a=VMCNT(12)@ph4-end retires SA0,SB0(s+1) [staged ph2(s-1), 6ph]
// Queue audit (in-order; 2 loads/halfset; steady s in [1,NT-3]):
//   pre-W_b: [B1(s)2,A1(s)2,A0B0(s+1)4,B1(s+1)2,A1(s+1)2]=12 -> 10 ✓
//   pre-W_c: 10 + A0B0(s+2)4 = 14 -> 12 ✓
//   pre-W_a: [A0B0(s+1)4,B1(s+1)2,A1(s+1)2,A0B0(s+2)4,B1(s+2)2]+A1(s+2)2=16 -> 12 ✓
// Tail: s=NT-2 (no stages): W_b=10 (12 outst), W_c=8 (10), W_a=4 (8).
//       s=NT-1: W_b=2 (4), W_c=0 (2), W_a skip.
// Prologue: tiles 0,1 fully staged in halfset order A0,B0,B1,A1 (matches
// steady issue order); VMCNT(8) retires tile 0; BAR. s=0,1 then satisfy the
// steady counts (waits are no-ops where the target already landed).
// WAR: each stage targets a region whose tile-s readers completed before the
// immediately preceding trailing BAR (ph2 stage vs ph1 reads of A0/B0; ph3
// vs ph2's B1; ph4 vs ph3's A1). RAW: each read follows the BAR preceded by
// its covering wait in all waves (collective rule).
// C stores PLAIN scalar (R8: NT defeats write-combining; float4 impossible:
// logits base d_out+1 is 4B-misaligned). Epilogue: CE partials first, C
// stores last, no trailing barrier (R9).
__global__ __launch_bounds__(512, 2) void gemm256(
    const __bf16* __restrict__ A, const __bf16* __restrict__ B,
    float* __restrict__ C, float* __restrict__ pm, float* __restrict__ ps) {
  __shared__ __align__(1024) unsigned char smem[2][65536];

  const int tid = threadIdx.x;
  const int bid = blockIdx.x;
  // Bijective XCD swizzle (2000 % 8 == 0), n-panel-major within XCD.
  const int wg = (bid & 7) * 250 + (bid >> 3);
  const int nblk = wg >> 4;  // 0..124
  const int mblk = wg & 15;  // 0..15
  const int m0 = mblk * 256;
  const int n0 = nblk * 256;

  const int w = tid >> 6;
  const int lane = tid & 63;
  const int wm = w >> 2;  // 0..1
  const int wn = w & 3;   // 0..3
  const int rl = lane & 15;
  const int cl = lane >> 4;
  const int srow = tid >> 3;  // staging row-within-64 block
  const int scc = tid & 7;    // staging dest chunk

  f32x4 acc[8][4];
#pragma unroll
  for (int i = 0; i < 8; ++i)
#pragma unroll
    for (int j = 0; j < 4; ++j) acc[i][j] = (f32x4){0.f, 0.f, 0.f, 0.f};

  // A halfset q: 64-row blocks at q*64 and 128+q*64.
  auto stA2 = [&](int nbuf, int kt, int q) {
#pragma unroll
    for (int j = 0; j < 2; ++j) {
      const int r0 = q * 64 + j * 128;
      const int row = r0 + srow;
      const int c = scc ^ (row & 7);
      GLDS16(A + (size_t)(m0 + row) * K_ + kt * 64 + c * 8,
             &smem[nbuf][r0 * 128 + tid * 16]);
    }
  };
  // B halfset q: 32-row stripes at {0,64,128,192}+q*32.
  auto stB2 = [&](int nbuf, int kt, int q) {
#pragma unroll
    for (int j = 0; j < 2; ++j) {
      const int cg = j * 512 + tid;
      const int rl_ = cg >> 3;
      const int row = ((rl_ >> 5) << 6) + q * 32 + (rl_ & 31);
      const int cc = cg & 7;
      const int c = cc ^ (row & 7);
      GLDS16(B + (size_t)(n0 + row) * K_ + kt * 64 + c * 8,
             &smem[nbuf][32768 + row * 128 + cc * 16]);
    }
  };
  auto ld = [&](const unsigned char* base, int row, int c) -> bf16x8 {
    return *(const bf16x8*)(base + row * 128 + (((c ^ row) & 7) << 4));
  };

  // Prologue: tiles 0 and 1 fully staged (order A0,B0,B1,A1 each);
  // VMCNT(8) lands tile 0, keeps tile 1's 8 loads in flight; BAR.
  stA2(0, 0, 0); stB2(0, 0, 0); stB2(0, 0, 1); stA2(0, 0, 1);
  stA2(1, 1, 0); stB2(1, 1, 0); stB2(1, 1, 1); stA2(1, 1, 1);
  VMCNT(8);
  BAR();

  bf16x8 al[4][2], ah[4][2], b0r[2][2], b1r[2][2];

  for (int s = 0; s < NT_; ++s) {
    const int cur = s & 1;
    const unsigned char* bA = smem[cur];
    const unsigned char* bB = smem[cur] + 32768;
    const bool s2 = (s + 2 < NT_);
    const bool last = (s == NT_ - 1);
    const bool pen = (s == NT_ - 2);

    // ---- ph1: read b0,a_lo (12); no stage; W_b retires SB1(s)
#pragma unroll
    for (int jj = 0; jj < 2; ++jj)
#pragma unroll
      for (int ks = 0; ks < 2; ++ks)
        b0r[jj][ks] = ld(bB, wn * 64 + jj * 16 + rl, ks * 4 + cl);
#pragma unroll
    for (int ii = 0; ii < 4; ++ii)
#pragma unroll
      for (int ks = 0; ks < 2; ++ks)
        al[ii][ks] = ld(bA, wm * 128 + ii * 16 + rl, ks * 4 + cl);
    BAR();
    LGKM0();
    PRIO1();
#pragma unroll
    for (int ii = 0; ii < 4; ++ii)
#pragma unroll
      for (int jj = 0; jj < 2; ++jj)
#pragma unroll
        for (int ks = 0; ks < 2; ++ks)
          acc[ii][jj] = __builtin_amdgcn_mfma_f32_16x16x32_bf16(
              al[ii][ks], b0r[jj][ks], acc[ii][jj], 0, 0, 0);
    PRIO0();
    if (last) { VMCNT(2); } else { VMCNT(10); }
    BAR();

    // ---- ph2: read b1 (4); stage SA0,SB0(s+2)->cur; W_c retires SA1(s)
#pragma unroll
    for (int jj = 0; jj < 2; ++jj)
#pragma unroll
      for (int ks = 0; ks < 2; ++ks)
        b1r[jj][ks] = ld(bB, wn * 64 + 32 + jj * 16 + rl, ks * 4 + cl);
    if (s2) { stA2(cur, s + 2, 0); stB2(cur, s + 2, 0); }
    BAR();
    LGKM0();
    PRIO1();
#pragma unroll
    for (int ii = 0; ii < 4; ++ii)
#pragma unroll
      for (int jj = 0; jj < 2; ++jj)
#pragma unroll
        for (int ks = 0; ks < 2; ++ks)
          acc[ii][2 + jj] = __builtin_amdgcn_mfma_f32_16x16x32_bf16(
              al[ii][ks], b1r[jj][ks], acc[ii][2 + jj], 0, 0, 0);
    PRIO0();
    if (s2) { VMCNT(12); } else if (pen) { VMCNT(8); } else { VMCNT(0); }
    BAR();

    // ---- ph3: read a_hi (8); stage SB1(s+2)->cur
#pragma unroll
    for (int ii = 0; ii < 4; ++ii)
#pragma unroll
      for (int ks = 0; ks < 2; ++ks)
        ah[ii][ks] = ld(bA, wm * 128 + 64 + ii * 16 + rl, ks * 4 + cl);
    if (s2) stB2(cur, s + 2, 1);
    BAR();
    LGKM0();
    PRIO1();
#pragma unroll
    for (int ii = 0; ii < 4; ++ii)
#pragma unroll
      for (int jj = 0; jj < 2; ++jj)
#pragma unroll
        for (int ks = 0; ks < 2; ++ks)
          acc[4 + ii][jj] = __builtin_amdgcn_mfma_f32_16x16x32_bf16(
              ah[ii][ks], b0r[jj][ks], acc[4 + ii][jj], 0, 0, 0);
    PRIO0();
    BAR();

    // ---- ph4: no reads; stage SA1(s+2)->cur; W_a retires SA0,SB0(s+1)
    if (s2) stA2(cur, s + 2, 1);
    BAR();
    PRIO1();
#pragma unroll
    for (int ii = 0; ii < 4; ++ii)
#pragma unroll
      for (int jj = 0; jj < 2; ++jj)
#pragma unroll
        for (int ks = 0; ks < 2; ++ks)
          acc[4 + ii][2 + jj] = __builtin_amdgcn_mfma_f32_16x16x32_bf16(
              ah[ii][ks], b1r[jj][ks], acc[4 + ii][2 + jj], 0, 0, 0);
    PRIO0();
    if (s2) { VMCNT(12); } else if (pen) { VMCNT(4); }
    BAR();
  }

  // ---- CE partials FIRST (no outstanding VMEM; barriers cheap).
  float* red = (float*)smem;               // [4][256] per-wn row maxes
  float* red2 = (float*)(smem[0] + 4096);  // [4][256] per-wn row sums
  {
    BAR();  // all waves past K-loop before LDS reuse
#pragma unroll
    for (int i = 0; i < 8; ++i)
#pragma unroll
      for (int r = 0; r < 4; ++r) {
        float v = fmaxf(fmaxf(acc[i][0][r], acc[i][1][r]),
                        fmaxf(acc[i][2][r], acc[i][3][r]));
#pragma unroll
        for (int o = 1; o < 16; o <<= 1) v = fmaxf(v, __shfl_xor(v, o));
        if (rl == 0) red[wn * 256 + wm * 128 + i * 16 + cl * 4 + r] = v;
      }
    BAR();
#pragma unroll
    for (int i = 0; i < 8; ++i)
#pragma unroll
      for (int r = 0; r < 4; ++r) {
        const int row = wm * 128 + i * 16 + cl * 4 + r;
        const float mx = fmaxf(fmaxf(red[row], red[256 + row]),
                               fmaxf(red[512 + row], red[768 + row]));
        float sv = __expf(acc[i][0][r] - mx) + __expf(acc[i][1][r] - mx) +
                   __expf(acc[i][2][r] - mx) + __expf(acc[i][3][r] - mx);
#pragma unroll
        for (int o = 1; o < 16; o <<= 1) sv += __shfl_xor(sv, o);
        if (rl == 0) red2[wn * 256 + row] = sv;
      }
    BAR();
    if (tid < 256) {
      const int row = tid;
      const float Mv = fmaxf(fmaxf(red[row], red[256 + row]),
                             fmaxf(red[512 + row], red[768 + row]));
      const float Sv = red2[row] + red2[256 + row] + red2[512 + row] +
                       red2[768 + row];
      pm[(size_t)(m0 + row) * NB_ + nblk] = Mv;
      ps[(size_t)(m0 + row) * NB_ + nblk] = Sv;
    }
  }

  // ---- C stores LAST, no trailing barrier: drain after s_endpgm.
  // C/D layout col = lane&15, row = (lane>>4)*4 + reg  [m89]
#pragma unroll
  for (int i = 0; i < 8; ++i)
#pragma unroll
    for (int j = 0; j < 4; ++j)
#pragma unroll
      for (int r = 0; r < 4; ++r) {
        const int grow = m0 + wm * 128 + i * 16 + cl * 4 + r;
        const int gcol = n0 + wn * 64 + j * 16 + rl;
        C[(size_t)grow * N_ + gcol] = acc[i][j][r];
      }
}

// ---------------------------------------------------------------- CE combine
__global__ __launch_bounds__(64) void ce_combine(
    const float* __restrict__ pm, const float* __restrict__ ps,
    const float* __restrict__ logits, const int* __restrict__ labels,
    float* __restrict__ nll) {
  const int r = blockIdx.x;  // 0..4093
  const int b = r / SM1;
  const int t = r - b * SM1;
  const int m = b * S_ + t;
  const int lane = threadIdx.x;
  float M = -3.4e38f, Ssum = 0.f;
  for (int j = lane; j < NB_; j += 64) {
    const float mj = pm[(size_t)m * NB_ + j];
    const float sj = ps[(size_t)m * NB_ + j];
    if (mj > M) { Ssum *= __expf(M - mj); M = mj; }
    Ssum += sj * __expf(mj - M);
  }
#pragma unroll
  for (int o = 32; o > 0; o >>= 1) {
    const float M2 = __shfl_xor(M, o), S2 = __shfl_xor(Ssum, o);
    const float mn = fmaxf(M, M2);
    Ssum = Ssum * __expf(M - mn) + S2 * __expf(M2 - mn);
    M = mn;
  }
  if (lane == 0) {
    const int lbl = labels[b * S_ + t + 1];
    nll[r] = M + __logf(Ssum) - logits[(size_t)m * N_ + lbl];
  }
}

// ---------------------------------------------------------------- fallback GEMM (fp32 in, 128^2)
__global__ __launch_bounds__(256) void gemm_fb(const float* __restrict__ Ap,
                                               const float* __restrict__ Bp,
                                               float* __restrict__ Cp) {
  __shared__ __align__(1024) unsigned char smem[2][16384];
  const int tid = threadIdx.x;
  const int bid = blockIdx.x;
  const int swz = (bid & 7) * 1000 + (bid >> 3);
  const int nblk = swz >> 5;
  const int mblk = swz & 31;
  const int m0 = mblk * 128;
  const int n0 = nblk * 128;
  const int w = tid >> 6, lane = tid & 63;
  const int wm = w >> 1, wn = w & 1;
  const int rl = lane & 15, cl = lane >> 4;

  f32x4 acc[4][4];
#pragma unroll
  for (int i = 0; i < 4; ++i)
#pragma unroll
    for (int j = 0; j < 4; ++j) acc[i][j] = (f32x4){0.f, 0.f, 0.f, 0.f};

  auto stage = [&](int buf, int kt) {
    const int k0 = kt * 32;
#pragma unroll
    for (int j = 0; j < 2; ++j) {
      const int t = j * 256 + tid;
      const int row = t >> 2;
      const int c = t & 3;
      const int rp = row >> 1;
      const int pp = ((row & 1) * 4 + c) ^ (rp & 7);
      const int lb = rp * 128 + pp * 16;
      {
        const float4* g = (const float4*)(Ap + (size_t)(m0 + row) * K_ + k0 + c * 8);
        float4 x = g[0], y = g[1];
        bf16x8 v;
        v[0] = (__bf16)x.x; v[1] = (__bf16)x.y; v[2] = (__bf16)x.z; v[3] = (__bf16)x.w;
        v[4] = (__bf16)y.x; v[5] = (__bf16)y.y; v[6] = (__bf16)y.z; v[7] = (__bf16)y.w;
        *(bf16x8*)(&smem[buf][lb]) = v;
      }
      {
        const float4* g = (const float4*)(Bp + (size_t)(n0 + row) * K_ + k0 + c * 8);
        float4 x = g[0], y = g[1];
        bf16x8 v;
        v[0] = (__bf16)x.x; v[1] = (__bf16)x.y; v[2] = (__bf16)x.z; v[3] = (__bf16)x.w;
        v[4] = (__bf16)y.x; v[5] = (__bf16)y.y; v[6] = (__bf16)y.z; v[7] = (__bf16)y.w;
        *(bf16x8*)(&smem[buf][8192 + lb]) = v;
      }
    }
  };
  auto ldfrag = [&](const unsigned char* base, int row, int c) -> bf16x8 {
    const int rp = row >> 1;
    const int pp = ((row & 1) * 4 + c) ^ (rp & 7);
    return *(const bf16x8*)(base + rp * 128 + pp * 16);
  };
  auto compute = [&](int buf) {
    const unsigned char* bA = smem[buf];
    const unsigned char* bB = smem[buf] + 8192;
    bf16x8 af[4], bfv[4];
#pragma unroll
    for (int i = 0; i < 4; ++i) af[i] = ldfrag(bA, wm * 64 + i * 16 + rl, cl);
#pragma unroll
    for (int j = 0; j < 4; ++j) bfv[j] = ldfrag(bB, wn * 64 + j * 16 + rl, cl);
#pragma unroll
    for (int i = 0; i < 4; ++i)
#pragma unroll
      for (int j = 0; j < 4; ++j)
        acc[i][j] = __builtin_amdgcn_mfma_f32_16x16x32_bf16(af[i], bfv[j],
                                                            acc[i][j], 0, 0, 0);
  };

  stage(0, 0);
  __syncthreads();
  for (int kt = 0; kt < 128; kt += 2) {
    if (kt + 1 < 128) stage(1, kt + 1);
    compute(0);
    __syncthreads();
    if (kt + 2 < 128) stage(0, kt + 2);
    compute(1);
    __syncthreads();
  }
#pragma unroll
  for (int i = 0; i < 4; ++i)
#pragma unroll
    for (int j = 0; j < 4; ++j)
#pragma unroll
      for (int r = 0; r < 4; ++r) {
        const int grow = m0 + wm * 64 + i * 16 + cl * 4 + r;
        const int gcol = n0 + wn * 64 + j * 16 + rl;
        Cp[(size_t)grow * N_ + gcol] = acc[i][j][r];
      }
}

// ---------------------------------------------------------------- CE loss (fallback, online 1-pass)
__global__ __launch_bounds__(256) void ce_rows(const float* __restrict__ logits,
                                               const int* __restrict__ labels,
                                               float* __restrict__ nll) {
  const int r = blockIdx.x;
  const int b = r / SM1;
  const int t = r - b * SM1;
  const float* row = logits + (size_t)(b * S_ + t) * N_;
  float m = -3.4e38f, s = 0.f;
  const float4* row4 = (const float4*)row;
  for (int i = threadIdx.x; i < 7936; i += 256) {
    float4 v = row4[i];
    float mx = fmaxf(fmaxf(v.x, v.y), fmaxf(v.z, v.w));
    if (mx > m) { s *= __expf(m - mx); m = mx; }
    s += __expf(v.x - m) + __expf(v.y - m) + __expf(v.z - m) + __expf(v.w - m);
  }
  {
    float v = row[31744 + threadIdx.x];
    if (v > m) { s *= __expf(m - v); m = v; }
    s += __expf(v - m);
  }
#pragma unroll
  for (int o = 32; o > 0; o >>= 1) {
    float m2 = __shfl_xor(m, o), s2 = __shfl_xor(s, o);
    float mn = fmaxf(m, m2);
    s = s * __expf(m - mn) + s2 * __expf(m2 - mn);
    m = mn;
  }
  __shared__ float rm[4], rs[4];
  if ((threadIdx.x & 63) == 0) { rm[threadIdx.x >> 6] = m; rs[threadIdx.x >> 6] = s; }
  __syncthreads();
  if (threadIdx.x == 0) {
    float M = fmaxf(fmaxf(rm[0], rm[1]), fmaxf(rm[2], rm[3]));
    float S = rs[0] * __expf(rm[0] - M) + rs[1] * __expf(rm[1] - M) +
              rs[2] * __expf(rm[2] - M) + rs[3] * __expf(rm[3] - M);
    nll[r] = M + __logf(S) - row[labels[b * S_ + t + 1]];
  }
}

__global__ __launch_bounds__(256) void reduce_loss(const float* __restrict__ nll,
                                                   float* __restrict__ out) {
  float s = 0.f;
  for (int i = threadIdx.x; i < NROWS; i += 256) s += nll[i];
#pragma unroll
  for (int o = 32; o > 0; o >>= 1) s += __shfl_xor(s, o);
  __shared__ float sb[4];
  if ((threadIdx.x & 63) == 0) sb[threadIdx.x >> 6] = s;
  __syncthreads();
  if (threadIdx.x == 0) out[0] = (sb[0] + sb[1] + sb[2] + sb[3]) / (float)NROWS;
}

// ---------------------------------------------------------------- launch
extern "C" void kernel_launch(void* const* d_in, const int* in_sizes, int n_in,
                              void* d_out, int out_size, void* d_ws,
                              size_t ws_size, hipStream_t stream) {
  const float* h = (const float*)d_in[0];
  const float* Wf = (const float*)d_in[1];
  const int* labels = (const int*)d_in[2];
  float* out = (float*)d_out;
  float* logits = out + 1;

  const size_t abytes = (size_t)M_ * K_ * 2;       // 33,554,432
  const size_t bbytes = (size_t)N_ * K_ * 2;       // 262,144,000
  const size_t pbytes = (size_t)M_ * NB_ * 4;      // 2,048,000
  const size_t need = abytes + bbytes + 2 * pbytes + (size_t)NROWS * 4;

  if (ws_size >= need) {
    unsigned char* base = (unsigned char*)d_ws;
    __bf16* hA = (__bf16*)base;
    __bf16* wB = (__bf16*)(base + abytes);
    float* pm = (float*)(base + abytes + bbytes);
    float* psum = (float*)(base + abytes + bbytes + pbytes);
    float* nll = (float*)(base + abytes + bbytes + 2 * pbytes);
    cvt_f32_to_bf16<<<2048, 256, 0, stream>>>(h, (bf16x8*)hA,
                                              (long)((size_t)M_ * K_ / 8));
    cvt_f32_to_bf16<<<4096, 256, 0, stream>>>(Wf, (bf16x8*)wB,
                                              (long)((size_t)N_ * K_ / 8));
    gemm256<<<2000, 512, 0, stream>>>(hA, wB, logits, pm, psum);
    ce_combine<<<NROWS, 64, 0, stream>>>(pm, psum, logits, labels, nll);
    reduce_loss<<<1, 256, 0, stream>>>(nll, out);
  } else {
    float* nll = (float*)d_ws;
    gemm_fb<<<8000, 256, 0, stream>>>(h, Wf, logits);
    ce_rows<<<4094, 256, 0, stream>>>(logits, labels, nll);
    reduce_loss<<<1, 256, 0, stream>>>(nll, out);
  }
}

// Round 15
// 1217.086 us; speedup vs baseline: 1.0080x; 1.0080x over previous
//
#include <hip/hip_runtime.h>
#include <hip/hip_bf16.h>

#define M_ 4096
#define N_ 32000
#define K_ 4096
#define S_ 2048
#define SM1 2047
#define NROWS 4094
#define NT_ 64   // K-tiles of BK=64
#define NB_ 125  // n-blocks per row

typedef __bf16 bf16x8 __attribute__((ext_vector_type(8)));
typedef float f32x4 __attribute__((ext_vector_type(4)));

#define GLDS16(g, l)                                                         \
  __builtin_amdgcn_global_load_lds(                                          \
      (__attribute__((address_space(1))) const void*)(g),                    \
      (__attribute__((address_space(3))) void*)(l), 16, 0, 0)
#define BAR() __builtin_amdgcn_s_barrier()
#define PRIO1() __builtin_amdgcn_s_setprio(1)
#define PRIO0() __builtin_amdgcn_s_setprio(0)
#define VMCNT(n) asm volatile("s_waitcnt vmcnt(" #n ")" ::: "memory")

// ---------------------------------------------------------------- cvt kernel
__global__ __launch_bounds__(256) void cvt_f32_to_bf16(
    const float* __restrict__ in, bf16x8* __restrict__ out, long n8) {
  long i0 = (long)blockIdx.x * blockDim.x + threadIdx.x;
  long stride = (long)gridDim.x * blockDim.x;
  for (long i = i0; i < n8; i += stride) {
    const float4* p = reinterpret_cast<const float4*>(in) + i * 2;
    float4 a = p[0];
    float4 b = p[1];
    bf16x8 v;
    v[0] = (__bf16)a.x; v[1] = (__bf16)a.y; v[2] = (__bf16)a.z; v[3] = (__bf16)a.w;
    v[4] = (__bf16)b.x; v[5] = (__bf16)b.y; v[6] = (__bf16)b.z; v[7] = (__bf16)b.w;
    out[i] = v;
  }
}

// ---------------------------------------------------------------- GEMM 256x256, BK=64 — v2 + boundary-read hiding (R15)
// C[m,n] = sum_k A[m,k]*B[n,k]. 512 thr = 8 waves (2m x 4n), per-wave 128x64
// = acc[8][4]. LDS 2 x 64KB (A 32K | B 32K), 128-B rows, slot = c ^ (row&7)
// (measured-conflict-free: linear GLDS dest + inverse-swz source).
//
// Halfsets (2 GLDS/thread each): SA0=A rows bit6==0 (al), SA1=bit6==1 (ah),
// SB0=B rows bit5==0 (b0), SB1=bit5==1 (b1).
//
// Cycle model (validated vs R5/R11/R13/R14): per tile per CU = MFMA ~2400cy
// + LDS ~2300-3000cy SERIALIZED ≈ 5200cy observed. v2's only overlap: ph2
// issues ah's 8 reads under the al*b1 MFMA. R15 extends this to the 12
// boundary reads: ph4 does {stage SB1; VMCNT(4); BAR; issue b0r,al(s+1);
// MFMA ah*b1 (independent)} so the reads drain under ph4's MFMA instead of
// stalling ph1(s+1).
//
// Tile s, staging tile s+1 (2 barriers/tile, R11 hazard audit):
//   ph1: stage SA0(s+1); MFMA al*b0; VMCNT(2) [SA1,SB1(s)]; BAR
//   ph2: stage SB0(s+1); read b1r(4),ah(8); MFMA al*b1   (ah drains under)
//   ph3: stage SA1(s+1); MFMA ah*b0
//   ph4: stage SB1(s+1); VMCNT(4) [SA0,SB0(s+1)]; BAR;
//        read b0r,al(s+1) (drain under MFMA); MFMA ah*b1
// vmcnt queue (in-order, 2/halfset): enter ph1: [SA1,SB1(s)]=4; +SA0(s+1)=6
// -> VMCNT(2) ✓. ph4 pre-wait: +SB0,SA1,SB1(s+1)=8 -> VMCNT(4) retires
// SA0,SB0(s+1) ✓ leaves SA1,SB1(s+1)=4 = ph1(s+1) entry ✓. Aging: all
// retired loads >=1.3 tiles-phases (~>=1300cy > 900cy HBM miss).
// WAR ph4 stage SB1(s+1)->nxt: last readers (b1r(s-1)@ph2(s-1)) complete
// before ph4(s-1)+ph1(s) barriers — 2-barrier separation (R11-proven).
// RAW: every cross-wave read after a BAR preceded by covering VMCNT in all
// waves (collective rule).
// C stores PLAIN scalar (R8: NT defeats write-combining; float4 impossible:
// logits base d_out+1 is 4B-misaligned). Epilogue: CE partials first, C
// stores last, no trailing barrier (R9).
__global__ __launch_bounds__(512, 2) void gemm256(
    const __bf16* __restrict__ A, const __bf16* __restrict__ B,
    float* __restrict__ C, float* __restrict__ pm, float* __restrict__ ps) {
  __shared__ __align__(1024) unsigned char smem[2][65536];

  const int tid = threadIdx.x;
  const int bid = blockIdx.x;
  // Bijective XCD swizzle (2000 % 8 == 0), n-panel-major within XCD.
  const int wg = (bid & 7) * 250 + (bid >> 3);
  const int nblk = wg >> 4;  // 0..124
  const int mblk = wg & 15;  // 0..15
  const int m0 = mblk * 256;
  const int n0 = nblk * 256;

  const int w = tid >> 6;
  const int lane = tid & 63;
  const int wm = w >> 2;  // 0..1
  const int wn = w & 3;   // 0..3
  const int rl = lane & 15;
  const int cl = lane >> 4;
  const int srow = tid >> 3;  // staging row-within-64 block
  const int scc = tid & 7;    // staging dest chunk

  f32x4 acc[8][4];
#pragma unroll
  for (int i = 0; i < 8; ++i)
#pragma unroll
    for (int j = 0; j < 4; ++j) acc[i][j] = (f32x4){0.f, 0.f, 0.f, 0.f};

  // A halfset q: 64-row blocks at q*64 and 128+q*64.
  auto stA2 = [&](int nbuf, int kt, int q) {
#pragma unroll
    for (int j = 0; j < 2; ++j) {
      const int r0 = q * 64 + j * 128;
      const int row = r0 + srow;
      const int c = scc ^ (row & 7);
      GLDS16(A + (size_t)(m0 + row) * K_ + kt * 64 + c * 8,
             &smem[nbuf][r0 * 128 + tid * 16]);
    }
  };
  // B halfset q: 32-row stripes at {0,64,128,192}+q*32.
  auto stB2 = [&](int nbuf, int kt, int q) {
#pragma unroll
    for (int j = 0; j < 2; ++j) {
      const int cg = j * 512 + tid;
      const int rl_ = cg >> 3;
      const int row = ((rl_ >> 5) << 6) + q * 32 + (rl_ & 31);
      const int cc = cg & 7;
      const int c = cc ^ (row & 7);
      GLDS16(B + (size_t)(n0 + row) * K_ + kt * 64 + c * 8,
             &smem[nbuf][32768 + row * 128 + cc * 16]);
    }
  };
  auto ld = [&](const unsigned char* base, int row, int c) -> bf16x8 {
    return *(const bf16x8*)(base + row * 128 + (((c ^ row) & 7) << 4));
  };

  // Prologue: tile 0 halfsets in consumption order; collective wait SA0,SB0;
  // leaves SA1,SB1(0)=4 in flight = steady-state ph1 entry.
  stA2(0, 0, 0); stB2(0, 0, 0); stA2(0, 0, 1); stB2(0, 0, 1);
  VMCNT(4);
  BAR();

  bf16x8 al[4][2], ah[4][2], b0r[2][2], b1r[2][2];
#pragma unroll
  for (int jj = 0; jj < 2; ++jj)
#pragma unroll
    for (int ks = 0; ks < 2; ++ks)
      b0r[jj][ks] = ld(smem[0] + 32768, wn * 64 + jj * 16 + rl, ks * 4 + cl);
#pragma unroll
  for (int ii = 0; ii < 4; ++ii)
#pragma unroll
    for (int ks = 0; ks < 2; ++ks)
      al[ii][ks] = ld(smem[0], wm * 128 + ii * 16 + rl, ks * 4 + cl);

  for (int s = 0; s < NT_; ++s) {
    const int cur = s & 1;
    const int nxt = cur ^ 1;
    const unsigned char* bA = smem[cur];
    const unsigned char* bB = smem[cur] + 32768;
    const bool st = (s + 1 < NT_);

    // ---- ph1: stage SA0(s+1); MFMA a_lo x b0; collective wait SA1,SB1(s)
    if (st) stA2(nxt, s + 1, 0);
    PRIO1();
#pragma unroll
    for (int ii = 0; ii < 4; ++ii)
#pragma unroll
      for (int jj = 0; jj < 2; ++jj)
#pragma unroll
        for (int ks = 0; ks < 2; ++ks)
          acc[ii][jj] = __builtin_amdgcn_mfma_f32_16x16x32_bf16(
              al[ii][ks], b0r[jj][ks], acc[ii][jj], 0, 0, 0);
    PRIO0();
    if (st) { VMCNT(2); } else { VMCNT(0); }
    BAR();

    // ---- ph2: stage SB0(s+1); read b1(first)+a_hi; MFMA a_lo x b1 (no BAR)
    if (st) stB2(nxt, s + 1, 0);
#pragma unroll
    for (int jj = 0; jj < 2; ++jj)
#pragma unroll
      for (int ks = 0; ks < 2; ++ks)
        b1r[jj][ks] = ld(bB, wn * 64 + 32 + jj * 16 + rl, ks * 4 + cl);
#pragma unroll
    for (int ii = 0; ii < 4; ++ii)
#pragma unroll
      for (int ks = 0; ks < 2; ++ks)
        ah[ii][ks] = ld(bA, wm * 128 + 64 + ii * 16 + rl, ks * 4 + cl);
    PRIO1();
#pragma unroll
    for (int ii = 0; ii < 4; ++ii)
#pragma unroll
      for (int jj = 0; jj < 2; ++jj)
#pragma unroll
        for (int ks = 0; ks < 2; ++ks)
          acc[ii][2 + jj] = __builtin_amdgcn_mfma_f32_16x16x32_bf16(
              al[ii][ks], b1r[jj][ks], acc[ii][2 + jj], 0, 0, 0);
    PRIO0();

    // ---- ph3: stage SA1(s+1); MFMA a_hi x b0  (no BAR)
    if (st) stA2(nxt, s + 1, 1);
    PRIO1();
#pragma unroll
    for (int ii = 0; ii < 4; ++ii)
#pragma unroll
      for (int jj = 0; jj < 2; ++jj)
#pragma unroll
        for (int ks = 0; ks < 2; ++ks)
          acc[4 + ii][jj] = __builtin_amdgcn_mfma_f32_16x16x32_bf16(
              ah[ii][ks], b0r[jj][ks], acc[4 + ii][jj], 0, 0, 0);
    PRIO0();

    // ---- ph4: stage SB1(s+1); boundary wait+BAR FIRST; issue next-tile
    //           reads; MFMA a_hi x b1 (independent — reads drain under it)
    if (st) {
      stB2(nxt, s + 1, 1);
      VMCNT(4);  // SA0,SB0(s+1) landed; SA1,SB1(s+1) stay in flight
      BAR();
      const unsigned char* nA = smem[nxt];
      const unsigned char* nB = smem[nxt] + 32768;
#pragma unroll
      for (int jj = 0; jj < 2; ++jj)
#pragma unroll
        for (int ks = 0; ks < 2; ++ks)
          b0r[jj][ks] = ld(nB, wn * 64 + jj * 16 + rl, ks * 4 + cl);
#pragma unroll
      for (int ii = 0; ii < 4; ++ii)
#pragma unroll
        for (int ks = 0; ks < 2; ++ks)
          al[ii][ks] = ld(nA, wm * 128 + ii * 16 + rl, ks * 4 + cl);
    }
    PRIO1();
#pragma unroll
    for (int ii = 0; ii < 4; ++ii)
#pragma unroll
      for (int jj = 0; jj < 2; ++jj)
#pragma unroll
        for (int ks = 0; ks < 2; ++ks)
          acc[4 + ii][2 + jj] = __builtin_amdgcn_mfma_f32_16x16x32_bf16(
              ah[ii][ks], b1r[jj][ks], acc[4 + ii][2 + jj], 0, 0, 0);
    PRIO0();
  }

  // ---- CE partials FIRST (no outstanding VMEM; barriers cheap).
  float* red = (float*)smem;               // [4][256] per-wn row maxes
  float* red2 = (float*)(smem[0] + 4096);  // [4][256] per-wn row sums
  {
    BAR();  // all waves past K-loop before LDS reuse
#pragma unroll
    for (int i = 0; i < 8; ++i)
#pragma unroll
      for (int r = 0; r < 4; ++r) {
        float v = fmaxf(fmaxf(acc[i][0][r], acc[i][1][r]),
                        fmaxf(acc[i][2][r], acc[i][3][r]));
#pragma unroll
        for (int o = 1; o < 16; o <<= 1) v = fmaxf(v, __shfl_xor(v, o));
        if (rl == 0) red[wn * 256 + wm * 128 + i * 16 + cl * 4 + r] = v;
      }
    BAR();
#pragma unroll
    for (int i = 0; i < 8; ++i)
#pragma unroll
      for (int r = 0; r < 4; ++r) {
        const int row = wm * 128 + i * 16 + cl * 4 + r;
        const float mx = fmaxf(fmaxf(red[row], red[256 + row]),
                               fmaxf(red[512 + row], red[768 + row]));
        float sv = __expf(acc[i][0][r] - mx) + __expf(acc[i][1][r] - mx) +
                   __expf(acc[i][2][r] - mx) + __expf(acc[i][3][r] - mx);
#pragma unroll
        for (int o = 1; o < 16; o <<= 1) sv += __shfl_xor(sv, o);
        if (rl == 0) red2[wn * 256 + row] = sv;
      }
    BAR();
    if (tid < 256) {
      const int row = tid;
      const float Mv = fmaxf(fmaxf(red[row], red[256 + row]),
                             fmaxf(red[512 + row], red[768 + row]));
      const float Sv = red2[row] + red2[256 + row] + red2[512 + row] +
                       red2[768 + row];
      pm[(size_t)(m0 + row) * NB_ + nblk] = Mv;
      ps[(size_t)(m0 + row) * NB_ + nblk] = Sv;
    }
  }

  // ---- C stores LAST, no trailing barrier: drain after s_endpgm.
  // C/D layout col = lane&15, row = (lane>>4)*4 + reg  [m89]
#pragma unroll
  for (int i = 0; i < 8; ++i)
#pragma unroll
    for (int j = 0; j < 4; ++j)
#pragma unroll
      for (int r = 0; r < 4; ++r) {
        const int grow = m0 + wm * 128 + i * 16 + cl * 4 + r;
        const int gcol = n0 + wn * 64 + j * 16 + rl;
        C[(size_t)grow * N_ + gcol] = acc[i][j][r];
      }
}

// ---------------------------------------------------------------- CE combine
__global__ __launch_bounds__(64) void ce_combine(
    const float* __restrict__ pm, const float* __restrict__ ps,
    const float* __restrict__ logits, const int* __restrict__ labels,
    float* __restrict__ nll) {
  const int r = blockIdx.x;  // 0..4093
  const int b = r / SM1;
  const int t = r - b * SM1;
  const int m = b * S_ + t;
  const int lane = threadIdx.x;
  float M = -3.4e38f, Ssum = 0.f;
  for (int j = lane; j < NB_; j += 64) {
    const float mj = pm[(size_t)m * NB_ + j];
    const float sj = ps[(size_t)m * NB_ + j];
    if (mj > M) { Ssum *= __expf(M - mj); M = mj; }
    Ssum += sj * __expf(mj - M);
  }
#pragma unroll
  for (int o = 32; o > 0; o >>= 1) {
    const float M2 = __shfl_xor(M, o), S2 = __shfl_xor(Ssum, o);
    const float mn = fmaxf(M, M2);
    Ssum = Ssum * __expf(M - mn) + S2 * __expf(M2 - mn);
    M = mn;
  }
  if (lane == 0) {
    const int lbl = labels[b * S_ + t + 1];
    nll[r] = M + __logf(Ssum) - logits[(size_t)m * N_ + lbl];
  }
}

// ---------------------------------------------------------------- fallback GEMM (fp32 in, 128^2)
__global__ __launch_bounds__(256) void gemm_fb(const float* __restrict__ Ap,
                                               const float* __restrict__ Bp,
                                               float* __restrict__ Cp) {
  __shared__ __align__(1024) unsigned char smem[2][16384];
  const int tid = threadIdx.x;
  const int bid = blockIdx.x;
  const int swz = (bid & 7) * 1000 + (bid >> 3);
  const int nblk = swz >> 5;
  const int mblk = swz & 31;
  const int m0 = mblk * 128;
  const int n0 = nblk * 128;
  const int w = tid >> 6, lane = tid & 63;
  const int wm = w >> 1, wn = w & 1;
  const int rl = lane & 15, cl = lane >> 4;

  f32x4 acc[4][4];
#pragma unroll
  for (int i = 0; i < 4; ++i)
#pragma unroll
    for (int j = 0; j < 4; ++j) acc[i][j] = (f32x4){0.f, 0.f, 0.f, 0.f};

  auto stage = [&](int buf, int kt) {
    const int k0 = kt * 32;
#pragma unroll
    for (int j = 0; j < 2; ++j) {
      const int t = j * 256 + tid;
      const int row = t >> 2;
      const int c = t & 3;
      const int rp = row >> 1;
      const int pp = ((row & 1) * 4 + c) ^ (rp & 7);
      const int lb = rp * 128 + pp * 16;
      {
        const float4* g = (const float4*)(Ap + (size_t)(m0 + row) * K_ + k0 + c * 8);
        float4 x = g[0], y = g[1];
        bf16x8 v;
        v[0] = (__bf16)x.x; v[1] = (__bf16)x.y; v[2] = (__bf16)x.z; v[3] = (__bf16)x.w;
        v[4] = (__bf16)y.x; v[5] = (__bf16)y.y; v[6] = (__bf16)y.z; v[7] = (__bf16)y.w;
        *(bf16x8*)(&smem[buf][lb]) = v;
      }
      {
        const float4* g = (const float4*)(Bp + (size_t)(n0 + row) * K_ + k0 + c * 8);
        float4 x = g[0], y = g[1];
        bf16x8 v;
        v[0] = (__bf16)x.x; v[1] = (__bf16)x.y; v[2] = (__bf16)x.z; v[3] = (__bf16)x.w;
        v[4] = (__bf16)y.x; v[5] = (__bf16)y.y; v[6] = (__bf16)y.z; v[7] = (__bf16)y.w;
        *(bf16x8*)(&smem[buf][8192 + lb]) = v;
      }
    }
  };
  auto ldfrag = [&](const unsigned char* base, int row, int c) -> bf16x8 {
    const int rp = row >> 1;
    const int pp = ((row & 1) * 4 + c) ^ (rp & 7);
    return *(const bf16x8*)(base + rp * 128 + pp * 16);
  };
  auto compute = [&](int buf) {
    const unsigned char* bA = smem[buf];
    const unsigned char* bB = smem[buf] + 8192;
    bf16x8 af[4], bfv[4];
#pragma unroll
    for (int i = 0; i < 4; ++i) af[i] = ldfrag(bA, wm * 64 + i * 16 + rl, cl);
#pragma unroll
    for (int j = 0; j < 4; ++j) bfv[j] = ldfrag(bB, wn * 64 + j * 16 + rl, cl);
#pragma unroll
    for (int i = 0; i < 4; ++i)
#pragma unroll
      for (int j = 0; j < 4; ++j)
        acc[i][j] = __builtin_amdgcn_mfma_f32_16x16x32_bf16(af[i], bfv[j],
                                                            acc[i][j], 0, 0, 0);
  };

  stage(0, 0);
  __syncthreads();
  for (int kt = 0; kt < 128; kt += 2) {
    if (kt + 1 < 128) stage(1, kt + 1);
    compute(0);
    __syncthreads();
    if (kt + 2 < 128) stage(0, kt + 2);
    compute(1);
    __syncthreads();
  }
#pragma unroll
  for (int i = 0; i < 4; ++i)
#pragma unroll
    for (int j = 0; j < 4; ++j)
#pragma unroll
      for (int r = 0; r < 4; ++r) {
        const int grow = m0 + wm * 64 + i * 16 + cl * 4 + r;
        const int gcol = n0 + wn * 64 + j * 16 + rl;
        Cp[(size_t)grow * N_ + gcol] = acc[i][j][r];
      }
}

// ---------------------------------------------------------------- CE loss (fallback, online 1-pass)
__global__ __launch_bounds__(256) void ce_rows(const float* __restrict__ logits,
                                               const int* __restrict__ labels,
                                               float* __restrict__ nll) {
  const int r = blockIdx.x;
  const int b = r / SM1;
  const int t = r - b * SM1;
  const float* row = logits + (size_t)(b * S_ + t) * N_;
  float m = -3.4e38f, s = 0.f;
  const float4* row4 = (const float4*)row;
  for (int i = threadIdx.x; i < 7936; i += 256) {
    float4 v = row4[i];
    float mx = fmaxf(fmaxf(v.x, v.y), fmaxf(v.z, v.w));
    if (mx > m) { s *= __expf(m - mx); m = mx; }
    s += __expf(v.x - m) + __expf(v.y - m) + __expf(v.z - m) + __expf(v.w - m);
  }
  {
    float v = row[31744 + threadIdx.x];
    if (v > m) { s *= __expf(m - v); m = v; }
    s += __expf(v - m);
  }
#pragma unroll
  for (int o = 32; o > 0; o >>= 1) {
    float m2 = __shfl_xor(m, o), s2 = __shfl_xor(s, o);
    float mn = fmaxf(m, m2);
    s = s * __expf(m - mn) + s2 * __expf(m2 - mn);
    m = mn;
  }
  __shared__ float rm[4], rs[4];
  if ((threadIdx.x & 63) == 0) { rm[threadIdx.x >> 6] = m; rs[threadIdx.x >> 6] = s; }
  __syncthreads();
  if (threadIdx.x == 0) {
    float M = fmaxf(fmaxf(rm[0], rm[1]), fmaxf(rm[2], rm[3]));
    float S = rs[0] * __expf(rm[0] - M) + rs[1] * __expf(rm[1] - M) +
              rs[2] * __expf(rm[2] - M) + rs[3] * __expf(rm[3] - M);
    nll[r] = M + __logf(S) - row[labels[b * S_ + t + 1]];
  }
}

__global__ __launch_bounds__(256) void reduce_loss(const float* __restrict__ nll,
                                                   float* __restrict__ out) {
  float s = 0.f;
  for (int i = threadIdx.x; i < NROWS; i += 256) s += nll[i];
#pragma unroll
  for (int o = 32; o > 0; o >>= 1) s += __shfl_xor(s, o);
  __shared__ float sb[4];
  if ((threadIdx.x & 63) == 0) sb[threadIdx.x >> 6] = s;
  __syncthreads();
  if (threadIdx.x == 0) out[0] = (sb[0] + sb[1] + sb[2] + sb[3]) / (float)NROWS;
}

// ---------------------------------------------------------------- launch
extern "C" void kernel_launch(void* const* d_in, const int* in_sizes, int n_in,
                              void* d_out, int out_size, void* d_ws,
                              size_t ws_size, hipStream_t stream) {
  const float* h = (const float*)d_in[0];
  const float* Wf = (const float*)d_in[1];
  const int* labels = (const int*)d_in[2];
  float* out = (float*)d_out;
  float* logits = out + 1;

  const size_t abytes = (size_t)M_ * K_ * 2;       // 33,554,432
  const size_t bbytes = (size_t)N_ * K_ * 2;       // 262,144,000
  const size_t pbytes = (size_t)M_ * NB_ * 4;      // 2,048,000
  const size_t need = abytes + bbytes + 2 * pbytes + (size_t)NROWS * 4;

  if (ws_size >= need) {
    unsigned char* base = (unsigned char*)d_ws;
    __bf16* hA = (__bf16*)base;
    __bf16* wB = (__bf16*)(base + abytes);
    float* pm = (float*)(base + abytes + bbytes);
    float* psum = (float*)(base + abytes + bbytes + pbytes);
    float* nll = (float*)(base + abytes + bbytes + 2 * pbytes);
    cvt_f32_to_bf16<<<2048, 256, 0, stream>>>(h, (bf16x8*)hA,
                                              (long)((size_t)M_ * K_ / 8));
    cvt_f32_to_bf16<<<4096, 256, 0, stream>>>(Wf, (bf16x8*)wB,
                                              (long)((size_t)N_ * K_ / 8));
    gemm256<<<2000, 512, 0, stream>>>(hA, wB, logits, pm, psum);
    ce_combine<<<NROWS, 64, 0, stream>>>(pm, psum, logits, labels, nll);
    reduce_loss<<<1, 256, 0, stream>>>(nll, out);
  } else {
    float* nll = (float*)d_ws;
    gemm_fb<<<8000, 256, 0, stream>>>(h, Wf, logits);
    ce_rows<<<4094, 256, 0, stream>>>(logits, labels, nll);
    reduce_loss<<<1, 256, 0, stream>>>(nll, out);
  }
}